// Round 7
// baseline (685.932 us; speedup 1.0000x reference)
//
#include <hip/hip_runtime.h>
#include <stdint.h>

// Problem constants (DGCNN propagation). Inputs/outputs FLOAT32; internals bf16 MFMA.
#define B_   16
#define CIN  384
#define GS   4096
#define GD   1024
#define M1   512
#define K2C  512
#define M2   384
#define NEG  0.2f
#define EPS_ 1e-5f

typedef __bf16 bf16x8 __attribute__((ext_vector_type(8)));
typedef float  f32x4  __attribute__((ext_vector_type(4)));

__device__ __forceinline__ float bf2f(ushort u) {
  uint32_t v = ((uint32_t)u) << 16;
  return __builtin_bit_cast(float, v);
}
__device__ __forceinline__ ushort f2bf(float f) {
  uint32_t x = __builtin_bit_cast(uint32_t, f);
  x += 0x7FFFu + ((x >> 16) & 1u);
  return (ushort)(x >> 16);
}
__device__ __forceinline__ float lo16f(uint32_t w) { return __builtin_bit_cast(float, w << 16); }
__device__ __forceinline__ float hi16f(uint32_t w) { return __builtin_bit_cast(float, w & 0xFFFF0000u); }

// ---------------- transpose+convert [b][C][N] f32 -> [b][N][C] bf16 ----------------
__global__ void k_transpose(const float* __restrict__ src, ushort* __restrict__ dst,
                            int Cdim, int N) {
  __shared__ ushort tile[32][33];
  int b = blockIdx.z;
  int n0 = blockIdx.x * 32, c0 = blockIdx.y * 32;
  const float* s = src + (size_t)b * Cdim * N;
  ushort* d = dst + (size_t)b * Cdim * N;
  int tx = threadIdx.x, ty = threadIdx.y;
#pragma unroll
  for (int i = 0; i < 4; i++) {
    int c = c0 + ty + i * 8;
    tile[ty + i * 8][tx] = f2bf(s[(size_t)c * N + n0 + tx]);
  }
  __syncthreads();
#pragma unroll
  for (int i = 0; i < 4; i++) {
    int n = n0 + ty + i * 8;
    d[(size_t)n * Cdim + c0 + tx] = tile[tx][ty + i * 8];
  }
}

// ---------------- weight prep ----------------
__global__ void k_wprep(const float* __restrict__ W, ushort* __restrict__ Wa,
                        ushort* __restrict__ Wd, int Khalf) {
  int t = blockIdx.x * 256 + threadIdx.x;
  int o = t / Khalf, c = t % Khalf;
  float wa = W[(size_t)o * 2 * Khalf + c];
  float wb = W[(size_t)o * 2 * Khalf + Khalf + c];
  Wa[t] = f2bf(wa);
  Wd[t] = f2bf(wb - wa);
}

// ---------------- kNN: wave-per-query, branchless top-4, shfl-butterfly merge ----------------
__device__ __forceinline__ void knn_lmin(float& ad, int& ai, float bd, int bi) {
  bool bl = (bd < ad) || (bd == ad && bi < ai);
  ad = bl ? bd : ad; ai = bl ? bi : ai;
}
__device__ __forceinline__ void knn_ce(float& ad, int& ai, float& bd, int& bi) {
  bool bl = (bd < ad) || (bd == ad && bi < ai);
  float na = bl ? bd : ad, nb = bl ? ad : bd;
  int nia = bl ? bi : ai, nib = bl ? ai : bi;
  ad = na; bd = nb; ai = nia; bi = nib;
}

template<int GSRC>
__global__ __launch_bounds__(256) void k_knn(const float* __restrict__ cq,
                                             const float* __restrict__ ck,
                                             int* __restrict__ idx) {
#pragma clang fp contract(off)
  int tid = threadIdx.x;
  int lane = tid & 63, wv = tid >> 6;
  int b = blockIdx.y;
  int q = blockIdx.x * 4 + wv;
  const float* cqb = cq + (size_t)b * 3 * GD;
  const float* ckb = ck + (size_t)b * 3 * GSRC;
  float qx = cqb[q], qy = cqb[GD + q], qz = cqb[2 * GD + q];
  float q2 = (qx * qx + qy * qy) + qz * qz;

  float d0 = 1e30f, d1 = 1e30f, d2 = 1e30f, d3 = 1e30f;
  int i0 = 0x7FFFFFFF, i1 = 0x7FFFFFFF, i2 = 0x7FFFFFFF, i3 = 0x7FFFFFFF;
  for (int j0 = lane * 4; j0 < GSRC; j0 += 256) {
    float4 X = *reinterpret_cast<const float4*>(ckb + j0);
    float4 Y = *reinterpret_cast<const float4*>(ckb + GSRC + j0);
    float4 Z = *reinterpret_cast<const float4*>(ckb + 2 * GSRC + j0);
#pragma unroll
    for (int u = 0; u < 4; u++) {
      float x = (&X.x)[u], y = (&Y.x)[u], z = (&Z.x)[u];
      float s2 = (x * x + y * y) + z * z;
      float dot = (qx * x + qy * y) + qz * z;
      float d = (q2 + s2) - 2.0f * dot;
      int j = j0 + u;
      bool c = d < d3;
      d3 = c ? d : d3; i3 = c ? j : i3;
      c = d3 < d2; { float t = d3; d3 = c ? d2 : d3; d2 = c ? t : d2;
                     int ti = i3; i3 = c ? i2 : i3; i2 = c ? ti : i2; }
      c = d2 < d1; { float t = d2; d2 = c ? d1 : d2; d1 = c ? t : d1;
                     int ti = i2; i2 = c ? i1 : i2; i1 = c ? ti : i1; }
      c = d1 < d0; { float t = d1; d1 = c ? d0 : d1; d0 = c ? t : d0;
                     int ti = i1; i1 = c ? i0 : i1; i0 = c ? ti : i0; }
    }
  }
#pragma unroll
  for (int off = 1; off < 64; off <<= 1) {
    float pd0 = __shfl_xor(d0, off), pd1 = __shfl_xor(d1, off);
    float pd2 = __shfl_xor(d2, off), pd3 = __shfl_xor(d3, off);
    int pi0 = __shfl_xor(i0, off), pi1 = __shfl_xor(i1, off);
    int pi2 = __shfl_xor(i2, off), pi3 = __shfl_xor(i3, off);
    knn_lmin(d0, i0, pd3, pi3);
    knn_lmin(d1, i1, pd2, pi2);
    knn_lmin(d2, i2, pd1, pi1);
    knn_lmin(d3, i3, pd0, pi0);
    knn_ce(d0, i0, d2, i2);
    knn_ce(d1, i1, d3, i3);
    knn_ce(d0, i0, d1, i1);
    knn_ce(d2, i2, d3, i3);
  }
  if (lane == 0) {
    int4 r; r.x = i0; r.y = i1; r.z = i2; r.w = i3;
    *reinterpret_cast<int4*>(&idx[((size_t)b * GD + q) * 4]) = r;
  }
}

// ---------------- bf16 MFMA GEMM with TRANSPOSED output: outT[b][n][m] ----------------
// 128x128 tile, BK=32, 4 waves, 4x4 mfma_f32_16x16x32_bf16 each.
// Transposed epilogue: acc regs are m-contiguous -> one ushort4/float4 store per (mi,ni).
template<bool OUT_BF16>
__global__ __launch_bounds__(256) void k_gemm(const ushort* __restrict__ W,
                                              const ushort* __restrict__ Xt,
                                              void* __restrict__ outv,
                                              int M, int Kd, int N) {
  __shared__ __align__(16) ushort As[128 * 40];
  __shared__ __align__(16) ushort Bs[128 * 40];
  int b = blockIdx.z;
  const ushort* X = Xt + (size_t)b * N * Kd;
  int m0 = blockIdx.y * 128, n0 = blockIdx.x * 128;
  int tid = threadIdx.x;
  int w = tid >> 6, lane = tid & 63;
  int lr = lane & 15, lq = lane >> 4;
  int mw = (w >> 1) * 64, nw = (w & 1) * 64;
  int r0 = tid >> 2, c0 = tid & 3;

  f32x4 zero = {0.f, 0.f, 0.f, 0.f};
  f32x4 acc[4][4];
#pragma unroll
  for (int mi = 0; mi < 4; mi++)
#pragma unroll
    for (int ni = 0; ni < 4; ni++) acc[mi][ni] = zero;

  int nk = Kd / 32;
  for (int kt = 0; kt < nk; kt++) {
    int kk = kt * 32;
    __syncthreads();
    uint4 va0 = *reinterpret_cast<const uint4*>(W + (size_t)(m0 + r0) * Kd + kk + c0 * 8);
    uint4 va1 = *reinterpret_cast<const uint4*>(W + (size_t)(m0 + r0 + 64) * Kd + kk + c0 * 8);
    uint4 vb0 = *reinterpret_cast<const uint4*>(X + (size_t)(n0 + r0) * Kd + kk + c0 * 8);
    uint4 vb1 = *reinterpret_cast<const uint4*>(X + (size_t)(n0 + r0 + 64) * Kd + kk + c0 * 8);
    *reinterpret_cast<uint4*>(&As[(r0)      * 40 + c0 * 8]) = va0;
    *reinterpret_cast<uint4*>(&As[(r0 + 64) * 40 + c0 * 8]) = va1;
    *reinterpret_cast<uint4*>(&Bs[(r0)      * 40 + c0 * 8]) = vb0;
    *reinterpret_cast<uint4*>(&Bs[(r0 + 64) * 40 + c0 * 8]) = vb1;
    __syncthreads();
    bf16x8 af[4], bfr[4];
#pragma unroll
    for (int mi = 0; mi < 4; mi++)
      af[mi] = *reinterpret_cast<const bf16x8*>(&As[(mw + mi * 16 + lr) * 40 + lq * 8]);
#pragma unroll
    for (int ni = 0; ni < 4; ni++)
      bfr[ni] = *reinterpret_cast<const bf16x8*>(&Bs[(nw + ni * 16 + lr) * 40 + lq * 8]);
#pragma unroll
    for (int mi = 0; mi < 4; mi++)
#pragma unroll
      for (int ni = 0; ni < 4; ni++)
        acc[mi][ni] = __builtin_amdgcn_mfma_f32_16x16x32_bf16(af[mi], bfr[ni], acc[mi][ni], 0, 0, 0);
  }
  // transposed store: outT[n][m], m-contiguous vectors
#pragma unroll
  for (int mi = 0; mi < 4; mi++) {
    int m = m0 + mw + mi * 16 + lq * 4;
#pragma unroll
    for (int ni = 0; ni < 4; ni++) {
      int n = n0 + nw + ni * 16 + lr;
      size_t off = (size_t)b * N * M + (size_t)n * M + m;
      if constexpr (OUT_BF16) {
        ushort4 v;
        v.x = f2bf(acc[mi][ni][0]); v.y = f2bf(acc[mi][ni][1]);
        v.z = f2bf(acc[mi][ni][2]); v.w = f2bf(acc[mi][ni][3]);
        *reinterpret_cast<ushort4*>((ushort*)outv + off) = v;
      } else {
        *reinterpret_cast<f32x4*>((float*)outv + off) = acc[mi][ni];
      }
    }
  }
}

// ---------------- GN1 stats: row-gather from A_T + BqT; per-group wave reduce ----------------
// block: 32 queries x 8 o-chunks(64). part[b][32][4][2]
__global__ __launch_bounds__(256) void k_stats1(const ushort* __restrict__ AT,
                                                const float* __restrict__ BqT,
                                                const int* __restrict__ idx1,
                                                float* __restrict__ part) {
  int b = blockIdx.y, gt = blockIdx.x;
  int tid = threadIdx.x;
  int gl = tid >> 3, c = tid & 7;
  int g = gt * 32 + gl, o0 = c * 64;
  int4 id = *reinterpret_cast<const int4*>(&idx1[((size_t)b * GD + g) * 4]);
  id.x &= (GS - 1); id.y &= (GS - 1); id.z &= (GS - 1); id.w &= (GS - 1);
  const ushort* base = AT + (size_t)b * GS * M1 + o0;
  const ushort* r[4] = { base + (size_t)id.x * M1, base + (size_t)id.y * M1,
                         base + (size_t)id.z * M1, base + (size_t)id.w * M1 };
  const float* bqr = BqT + ((size_t)b * GD + g) * M1 + o0;
  float sum = 0.f, ssq = 0.f;
#pragma unroll 2
  for (int j = 0; j < 64; j += 8) {
    f32x4 bqa = *reinterpret_cast<const f32x4*>(bqr + j);
    f32x4 bqb = *reinterpret_cast<const f32x4*>(bqr + j + 4);
#pragma unroll
    for (int k = 0; k < 4; k++) {
      uint4 av = *reinterpret_cast<const uint4*>(r[k] + j);
      float y0 = lo16f(av.x) + bqa[0], y1 = hi16f(av.x) + bqa[1];
      float y2 = lo16f(av.y) + bqa[2], y3 = hi16f(av.y) + bqa[3];
      float y4 = lo16f(av.z) + bqb[0], y5 = hi16f(av.z) + bqb[1];
      float y6 = lo16f(av.w) + bqb[2], y7 = hi16f(av.w) + bqb[3];
      sum += ((y0 + y1) + (y2 + y3)) + ((y4 + y5) + (y6 + y7));
      ssq += ((y0 * y0 + y1 * y1) + (y2 * y2 + y3 * y3)) +
             ((y4 * y4 + y5 * y5) + (y6 * y6 + y7 * y7));
    }
  }
  // wave reduce over bits {0,3,4,5}: fold 8 queries + c-pair -> per-group (c>>1)
  sum += __shfl_xor(sum, 8);  ssq += __shfl_xor(ssq, 8);
  sum += __shfl_xor(sum, 16); ssq += __shfl_xor(ssq, 16);
  sum += __shfl_xor(sum, 32); ssq += __shfl_xor(ssq, 32);
  sum += __shfl_xor(sum, 1);  ssq += __shfl_xor(ssq, 1);
  __shared__ float sg[4][4], qg[4][4];   // [wave][group]
  int lane = tid & 63, wv = tid >> 6;
  if ((lane & 57) == 0) { sg[wv][lane >> 1] = sum; qg[wv][lane >> 1] = ssq; }
  __syncthreads();
  if (tid < 4) {
    float s = sg[0][tid] + sg[1][tid] + sg[2][tid] + sg[3][tid];
    float q = qg[0][tid] + qg[1][tid] + qg[2][tid] + qg[3][tid];
    int key = (((size_t)b * 32 + gt) * 4 + tid) * 2;
    part[key] = s; part[key + 1] = q;
  }
}

// ---------------- GN2 stats: fp32 rows, 48-chunk, groups of 96 ----------------
__global__ __launch_bounds__(256) void k_stats2(const float* __restrict__ A2T,
                                                const float* __restrict__ B2qT,
                                                const int* __restrict__ idx2,
                                                float* __restrict__ part) {
  int b = blockIdx.y, gt = blockIdx.x;
  int tid = threadIdx.x;
  int gl = tid >> 3, c = tid & 7;
  int g = gt * 32 + gl, o0 = c * 48;
  int4 id = *reinterpret_cast<const int4*>(&idx2[((size_t)b * GD + g) * 4]);
  id.x &= (GD - 1); id.y &= (GD - 1); id.z &= (GD - 1); id.w &= (GD - 1);
  const float* base = A2T + (size_t)b * GD * M2 + o0;
  const float* r[4] = { base + (size_t)id.x * M2, base + (size_t)id.y * M2,
                        base + (size_t)id.z * M2, base + (size_t)id.w * M2 };
  const float* bqr = B2qT + ((size_t)b * GD + g) * M2 + o0;
  float sum = 0.f, ssq = 0.f;
  for (int j = 0; j < 48; j += 8) {
    f32x4 bqa = *reinterpret_cast<const f32x4*>(bqr + j);
    f32x4 bqb = *reinterpret_cast<const f32x4*>(bqr + j + 4);
#pragma unroll
    for (int k = 0; k < 4; k++) {
      f32x4 aa = *reinterpret_cast<const f32x4*>(r[k] + j);
      f32x4 ab = *reinterpret_cast<const f32x4*>(r[k] + j + 4);
      float y0 = aa[0] + bqa[0], y1 = aa[1] + bqa[1], y2 = aa[2] + bqa[2], y3 = aa[3] + bqa[3];
      float y4 = ab[0] + bqb[0], y5 = ab[1] + bqb[1], y6 = ab[2] + bqb[2], y7 = ab[3] + bqb[3];
      sum += ((y0 + y1) + (y2 + y3)) + ((y4 + y5) + (y6 + y7));
      ssq += ((y0 * y0 + y1 * y1) + (y2 * y2 + y3 * y3)) +
             ((y4 * y4 + y5 * y5) + (y6 * y6 + y7 * y7));
    }
  }
  sum += __shfl_xor(sum, 8);  ssq += __shfl_xor(ssq, 8);
  sum += __shfl_xor(sum, 16); ssq += __shfl_xor(ssq, 16);
  sum += __shfl_xor(sum, 32); ssq += __shfl_xor(ssq, 32);
  sum += __shfl_xor(sum, 1);  ssq += __shfl_xor(ssq, 1);
  __shared__ float sg[4][4], qg[4][4];
  int lane = tid & 63, wv = tid >> 6;
  if ((lane & 57) == 0) { sg[wv][lane >> 1] = sum; qg[wv][lane >> 1] = ssq; }
  __syncthreads();
  if (tid < 4) {
    float s = sg[0][tid] + sg[1][tid] + sg[2][tid] + sg[3][tid];
    float q = qg[0][tid] + qg[1][tid] + qg[2][tid] + qg[3][tid];
    int key = (((size_t)b * 32 + gt) * 4 + tid) * 2;
    part[key] = s; part[key + 1] = q;
  }
}

__global__ void k_statsfin(const float* __restrict__ part, float* __restrict__ fin, float invN) {
  int t = threadIdx.x;  // 64 = 16 b * 4 groups
  int b = t >> 2, u = t & 3;
  float s = 0.f, q = 0.f;
  for (int j = 0; j < 32; j++) {
    int key = (((size_t)b * 32 + j) * 4 + u) * 2;
    s += part[key]; q += part[key + 1];
  }
  float mean = s * invN;
  float var = q * invN - mean * mean;
  float rstd = 1.0f / sqrtf(fmaxf(var, 0.0f) + EPS_);
  fin[t * 2] = mean; fin[t * 2 + 1] = rstd;
}

// ---------------- h: row-gather, max_k leaky(GN1), write hT[b][g][o] contiguous ----------------
__global__ __launch_bounds__(256) void k_h(const ushort* __restrict__ AT,
                                           const float* __restrict__ BqT,
                                           const int* __restrict__ idx1,
                                           const float* __restrict__ fin,
                                           const float* __restrict__ gam,
                                           const float* __restrict__ bet,
                                           ushort* __restrict__ hT) {
  int b = blockIdx.y, gt = blockIdx.x;
  int tid = threadIdx.x;
  int gl = tid >> 3, c = tid & 7;
  int g = gt * 32 + gl, o0 = c * 64;
  int4 id = *reinterpret_cast<const int4*>(&idx1[((size_t)b * GD + g) * 4]);
  id.x &= (GS - 1); id.y &= (GS - 1); id.z &= (GS - 1); id.w &= (GS - 1);
  const ushort* base = AT + (size_t)b * GS * M1 + o0;
  const ushort* r[4] = { base + (size_t)id.x * M1, base + (size_t)id.y * M1,
                         base + (size_t)id.z * M1, base + (size_t)id.w * M1 };
  const float* bqr = BqT + ((size_t)b * GD + g) * M1 + o0;
  float mean = fin[(b * 4 + (c >> 1)) * 2];
  float rstd = fin[(b * 4 + (c >> 1)) * 2 + 1];
  ushort* ho = hT + ((size_t)b * GD + g) * K2C + o0;
#pragma unroll 2
  for (int j = 0; j < 64; j += 8) {
    f32x4 bqa = *reinterpret_cast<const f32x4*>(bqr + j);
    f32x4 bqb = *reinterpret_cast<const f32x4*>(bqr + j + 4);
    f32x4 ga_a = *reinterpret_cast<const f32x4*>(gam + o0 + j);
    f32x4 ga_b = *reinterpret_cast<const f32x4*>(gam + o0 + j + 4);
    f32x4 be_a = *reinterpret_cast<const f32x4*>(bet + o0 + j);
    f32x4 be_b = *reinterpret_cast<const f32x4*>(bet + o0 + j + 4);
    float sc[8], sh[8], m[8];
#pragma unroll
    for (int i = 0; i < 4; i++) {
      sc[i] = rstd * ga_a[i];     sh[i] = be_a[i] - mean * sc[i];
      sc[4 + i] = rstd * ga_b[i]; sh[4 + i] = be_b[i] - mean * sc[4 + i];
      m[i] = -1e30f; m[4 + i] = -1e30f;
    }
#pragma unroll
    for (int k = 0; k < 4; k++) {
      uint4 av = *reinterpret_cast<const uint4*>(r[k] + j);
      float y[8];
      y[0] = lo16f(av.x) + bqa[0]; y[1] = hi16f(av.x) + bqa[1];
      y[2] = lo16f(av.y) + bqa[2]; y[3] = hi16f(av.y) + bqa[3];
      y[4] = lo16f(av.z) + bqb[0]; y[5] = hi16f(av.z) + bqb[1];
      y[6] = lo16f(av.w) + bqb[2]; y[7] = hi16f(av.w) + bqb[3];
#pragma unroll
      for (int i = 0; i < 8; i++) {
        float v = y[i] * sc[i] + sh[i];
        v = fmaxf(v, NEG * v);        // leaky relu
        m[i] = fmaxf(m[i], v);
      }
    }
    uint4 outw;
    outw.x = ((uint32_t)f2bf(m[1]) << 16) | f2bf(m[0]);
    outw.y = ((uint32_t)f2bf(m[3]) << 16) | f2bf(m[2]);
    outw.z = ((uint32_t)f2bf(m[5]) << 16) | f2bf(m[4]);
    outw.w = ((uint32_t)f2bf(m[7]) << 16) | f2bf(m[6]);
    *reinterpret_cast<uint4*>(ho + j) = outw;
  }
}

// ---------------- final: row-gather, max_k leaky(GN2), write out[b][o][g] ----------------
__global__ __launch_bounds__(256) void k_out(const float* __restrict__ A2T,
                                             const float* __restrict__ B2qT,
                                             const int* __restrict__ idx2,
                                             const float* __restrict__ fin,
                                             const float* __restrict__ gam,
                                             const float* __restrict__ bet,
                                             float* __restrict__ out) {
  int b = blockIdx.y, gt = blockIdx.x;
  int tid = threadIdx.x;
  int gl = tid >> 3, c = tid & 7;
  int g = gt * 32 + gl, o0 = c * 48;
  int4 id = *reinterpret_cast<const int4*>(&idx2[((size_t)b * GD + g) * 4]);
  id.x &= (GD - 1); id.y &= (GD - 1); id.z &= (GD - 1); id.w &= (GD - 1);
  const float* base = A2T + (size_t)b * GD * M2 + o0;
  const float* r[4] = { base + (size_t)id.x * M2, base + (size_t)id.y * M2,
                        base + (size_t)id.z * M2, base + (size_t)id.w * M2 };
  const float* bqr = B2qT + ((size_t)b * GD + g) * M2 + o0;
  float mean = fin[(b * 4 + (c >> 1)) * 2];
  float rstd = fin[(b * 4 + (c >> 1)) * 2 + 1];
  float* oo = out + (size_t)b * M2 * GD + g;
  for (int j = 0; j < 48; j += 8) {
    f32x4 bqa = *reinterpret_cast<const f32x4*>(bqr + j);
    f32x4 bqb = *reinterpret_cast<const f32x4*>(bqr + j + 4);
    f32x4 ga_a = *reinterpret_cast<const f32x4*>(gam + o0 + j);
    f32x4 ga_b = *reinterpret_cast<const f32x4*>(gam + o0 + j + 4);
    f32x4 be_a = *reinterpret_cast<const f32x4*>(bet + o0 + j);
    f32x4 be_b = *reinterpret_cast<const f32x4*>(bet + o0 + j + 4);
    float sc[8], sh[8], m[8];
#pragma unroll
    for (int i = 0; i < 4; i++) {
      sc[i] = rstd * ga_a[i];     sh[i] = be_a[i] - mean * sc[i];
      sc[4 + i] = rstd * ga_b[i]; sh[4 + i] = be_b[i] - mean * sc[4 + i];
      m[i] = -1e30f; m[4 + i] = -1e30f;
    }
#pragma unroll
    for (int k = 0; k < 4; k++) {
      f32x4 aa = *reinterpret_cast<const f32x4*>(r[k] + j);
      f32x4 ab = *reinterpret_cast<const f32x4*>(r[k] + j + 4);
      float y[8] = { aa[0] + bqa[0], aa[1] + bqa[1], aa[2] + bqa[2], aa[3] + bqa[3],
                     ab[0] + bqb[0], ab[1] + bqb[1], ab[2] + bqb[2], ab[3] + bqb[3] };
#pragma unroll
      for (int i = 0; i < 8; i++) {
        float v = y[i] * sc[i] + sh[i];
        v = fmaxf(v, NEG * v);
        m[i] = fmaxf(m[i], v);
      }
    }
#pragma unroll
    for (int i = 0; i < 8; i++)
      oo[(size_t)(o0 + j + i) * GD] = m[i];
  }
}

extern "C" void kernel_launch(void* const* d_in, const int* in_sizes, int n_in,
                              void* d_out, int out_size, void* d_ws, size_t ws_size,
                              hipStream_t stream) {
  (void)in_sizes; (void)n_in; (void)out_size;
  const float* coor  = (const float*)d_in[0];
  const float* f     = (const float*)d_in[1];
  const float* coorq = (const float*)d_in[2];
  const float* fq    = (const float*)d_in[3];
  const float* W1    = (const float*)d_in[4];
  const float* g1    = (const float*)d_in[5];
  const float* b1    = (const float*)d_in[6];
  const float* W2    = (const float*)d_in[7];
  const float* g2    = (const float*)d_in[8];
  const float* b2    = (const float*)d_in[9];

  if (ws_size < 182468608u) return;

  char* ws = (char*)d_ws;
  int*    idx1 = (int*)(ws + 0);            // 256 KB
  int*    idx2 = (int*)(ws + 0x40000);      // 256 KB
  ushort* W1a  = (ushort*)(ws + 0x80000);           // 512*384 bf16
  ushort* W1d  = W1a + (size_t)512 * 384;
  ushort* W2a  = W1d + (size_t)512 * 384;
  ushort* W2d  = W2a + (size_t)384 * 512;
  ushort* fT   = W2d + (size_t)384 * 512;           // [16][4096][384] bf16
  ushort* fqT  = fT + (size_t)B_ * GS * CIN;        // [16][1024][384] bf16
  ushort* AT   = fqT + (size_t)B_ * GD * CIN;       // [16][4096][512] bf16 (transposed GEMM1a out)
  float*  BqT  = (float*)(AT + (size_t)B_ * GS * M1);   // [16][1024][512] f32
  ushort* hT   = (ushort*)((char*)BqT + (size_t)B_ * GD * M1 * 4); // [16][1024][512] bf16
  float*  A2T  = (float*)fT;                        // [16][1024][384] f32 (aliases dead fT)
  float*  B2qT = A2T + (size_t)B_ * GD * M2;
  // stats partials/finals live in the dead fqT region (dead after GEMM1b)
  float*  part1 = (float*)fqT;        // [16][32][4][2] = 16 KB
  float*  part2 = part1 + 4096;       // 16 KB
  float*  fin1  = part2 + 4096;       // [16][4][2]
  float*  fin2  = fin1 + 128;

  // 1. transposes (+f32->bf16) + weight prep
  k_transpose<<<dim3(GS / 32, CIN / 32, B_), dim3(32, 8), 0, stream>>>(f, fT, CIN, GS);
  k_transpose<<<dim3(GD / 32, CIN / 32, B_), dim3(32, 8), 0, stream>>>(fq, fqT, CIN, GD);
  k_wprep<<<dim3(512 * 384 / 256), 256, 0, stream>>>(W1, W1a, W1d, 384);
  k_wprep<<<dim3(384 * 512 / 256), 256, 0, stream>>>(W2, W2a, W2d, 512);

  // 2. kNN index sets
  k_knn<GS><<<dim3(GD / 4, B_), 256, 0, stream>>>(coorq, coor, idx1);
  k_knn<GD><<<dim3(GD / 4, B_), 256, 0, stream>>>(coorq, coorq, idx2);

  // 3. block1 GEMMs -> transposed outputs (rows = channels per point)
  k_gemm<true ><<<dim3(GS / 128, M1 / 128, B_), 256, 0, stream>>>(W1a, fT, AT, M1, CIN, GS);
  k_gemm<false><<<dim3(GD / 128, M1 / 128, B_), 256, 0, stream>>>(W1d, fqT, BqT, M1, CIN, GD);

  // 4. GN1 stats + h (row-gathers; hT written contiguous)
  k_stats1<<<dim3(GD / 32, B_), 256, 0, stream>>>(AT, BqT, idx1, part1);
  k_statsfin<<<1, 64, 0, stream>>>(part1, fin1, 1.0f / 524288.0f);
  k_h<<<dim3(GD / 32, B_), 256, 0, stream>>>(AT, BqT, idx1, fin1, g1, b1, hT);

  // 5. block2 GEMMs -> transposed f32 outputs (alias dead fT region)
  k_gemm<false><<<dim3(GD / 128, M2 / 128, B_), 256, 0, stream>>>(W2a, hT, A2T, M2, K2C, GD);
  k_gemm<false><<<dim3(GD / 128, M2 / 128, B_), 256, 0, stream>>>(W2d, hT, B2qT, M2, K2C, GD);

  // 6. GN2 stats + final output
  k_stats2<<<dim3(GD / 32, B_), 256, 0, stream>>>(A2T, B2qT, idx2, part2);
  k_statsfin<<<1, 64, 0, stream>>>(part2, fin2, 1.0f / 393216.0f);
  k_out<<<dim3(GD / 32, B_), 256, 0, stream>>>(A2T, B2qT, idx2, fin2, g2, b2, (float*)d_out);
}